// Round 2
// baseline (1120.591 us; speedup 1.0000x reference)
//
#include <hip/hip_runtime.h>
#include <hip/hip_bf16.h>
#include <stdint.h>
#include <stdio.h>

// Problem dims (fixed by the reference)
#define T_SEQ  2048
#define BATCH  2
#define NROWS  4096   // B*T
#define EMBED  512
#define HIDDEN 1024
#define VOCAB  32000
#define NCHUNK 32
#define CHLEN  64     // T_SEQ / NCHUNK

typedef __bf16 bf16x8 __attribute__((ext_vector_type(8)));
typedef float  f32x4  __attribute__((ext_vector_type(4)));

__device__ __forceinline__ float b2f(unsigned short h) {
  union { unsigned int u; float f; } v; v.u = ((unsigned int)h) << 16; return v.f;
}
__device__ __forceinline__ unsigned short f2b(float f) {
  union { float f; unsigned int u; } v; v.f = f;
  unsigned int u = v.u;
  u += 0x7fffu + ((u >> 16) & 1u);   // round-to-nearest-even
  return (unsigned short)(u >> 16);
}

// ---------------- gather: emb[row,:] = bf16(E[tokens[row],:]) ----------------
__global__ void gather_kernel(const int* __restrict__ tokens,
                              const float* __restrict__ E,
                              unsigned short* __restrict__ emb) {
  const int row = blockIdx.x;
  const int tok = tokens[row];
  const float2 v = ((const float2*)(E + (size_t)tok * EMBED))[threadIdx.x];
  const uint32_t packed = (uint32_t)f2b(v.x) | ((uint32_t)f2b(v.y) << 16);
  ((uint32_t*)(emb + (size_t)row * EMBED))[threadIdx.x] = packed;  // 256 thr * 2 bf16
}

// ------------- prefix mean, 3-pass chunked scan -------------
// hist[t] = mean(emb[0:t]) = csum[t-1]/t for t>=1; hist[0] = emb[0]
__global__ void scan_sum_kernel(const unsigned short* __restrict__ emb,
                                float* __restrict__ csum) {
  const int bc = blockIdx.x;                 // b*NCHUNK + c
  const int d  = threadIdx.x;
  const unsigned short* e = emb + ((size_t)bc * CHLEN) * EMBED + d;
  float s = 0.f;
  #pragma unroll 8
  for (int i = 0; i < CHLEN; ++i) s += b2f(e[(size_t)i * EMBED]);
  csum[(size_t)bc * EMBED + d] = s;
}

__global__ void scan_excl_kernel(float* __restrict__ csum) {
  const int b = blockIdx.x;
  const int d = threadIdx.x;
  float run = 0.f;
  for (int c = 0; c < NCHUNK; ++c) {
    const size_t idx = ((size_t)b * NCHUNK + c) * EMBED + d;
    const float v = csum[idx];
    csum[idx] = run;
    run += v;
  }
}

__global__ void scan_emit_kernel(const unsigned short* __restrict__ emb,
                                 const float* __restrict__ csum,
                                 unsigned short* __restrict__ hist) {
  const int bc = blockIdx.x;                 // b*NCHUNK + c
  const int c  = bc & (NCHUNK - 1);
  const int d  = threadIdx.x;
  const unsigned short* e = emb  + ((size_t)bc * CHLEN) * EMBED + d;
  unsigned short*       h = hist + ((size_t)bc * CHLEN) * EMBED + d;
  float sum = csum[(size_t)bc * EMBED + d];  // exclusive prefix Σ emb[0 .. c*CHLEN-1]
  #pragma unroll 8
  for (int i = 0; i < CHLEN; ++i) {
    const int t = c * CHLEN + i;             // global timestep within batch
    h[(size_t)i * EMBED] = (t == 0) ? e[0] : f2b(sum / (float)t);
    sum += b2f(e[(size_t)i * EMBED]);
  }
}

// ------------- transpose + f32->bf16 cast: out[C,R] = bf16(in[R,C]^T) -------------
__global__ void transpose_cast_kernel(const float* __restrict__ in,
                                      unsigned short* __restrict__ out,
                                      int R, int C) {
  __shared__ float tile[32][33];             // +1 pad breaks bank conflicts
  const int tx = threadIdx.x & 31;
  const int ty = threadIdx.x >> 5;           // 0..7
  const int r0 = blockIdx.y * 32, c0 = blockIdx.x * 32;
  #pragma unroll
  for (int i = 0; i < 32; i += 8)
    tile[ty + i][tx] = in[(size_t)(r0 + ty + i) * C + (c0 + tx)];
  __syncthreads();
  #pragma unroll
  for (int i = 0; i < 32; i += 8)
    out[(size_t)(c0 + ty + i) * R + (r0 + tx)] = f2b(tile[tx][ty + i]);
}

// ---------------- MFMA GEMM: out = f(A @ BT^T + bias) ----------------
// A [M,K] bf16 row-major, BT [N,K] bf16 row-major (B pre-transposed).
// MODE 0: relu -> bf16 ; MODE 1: relu -> f32 ; MODE 2: (x+bias)*0.1 -> f32
#define BM 128
#define BN 128
#define BK 32

__device__ __forceinline__ void async16(unsigned short* lds, const unsigned short* g) {
  __builtin_amdgcn_global_load_lds(
      (const __attribute__((address_space(1))) void*)g,
      (__attribute__((address_space(3))) void*)lds, 16, 0, 0);
}

template<int MODE>
__global__ __launch_bounds__(256) void gemm_bt_kernel(
    const unsigned short* __restrict__ A,
    const unsigned short* __restrict__ BT,
    const float* __restrict__ bias,
    void* __restrict__ out, int M, int N, int K, int ldOut, int colOff) {
  __shared__ unsigned short As[BM * BK];   // [128][32] row-major
  __shared__ unsigned short Bs[BN * BK];   // [128][32] row-major (n-major)

  const int tid  = threadIdx.x;
  const int wave = tid >> 6;
  const int lane = tid & 63;
  const int m0 = blockIdx.y * BM;
  const int n0 = blockIdx.x * BN;
  const int wm = (wave & 1) * 64;          // wave quadrant (2x2)
  const int wn = (wave >> 1) * 64;

  // staging: each wave stages its own 32-row chunk of each tile (2 instrs x 1KB)
  const int srow = (wave << 5) + (lane >> 2);   // +16 rows on 2nd instr
  const int scol = (lane & 3) << 3;             // 4 lanes x 8 bf16 = 32 k
  const unsigned short* aSrc = A  + (size_t)(m0 + srow) * K + scol;
  const unsigned short* bSrc = BT + (size_t)(n0 + srow) * K + scol;
  unsigned short* aDst = As + (wave << 5) * BK;  // wave-uniform LDS base
  unsigned short* bDst = Bs + (wave << 5) * BK;

  f32x4 acc[4][4];
  #pragma unroll
  for (int i = 0; i < 4; ++i)
    #pragma unroll
    for (int j = 0; j < 4; ++j)
      acc[i][j] = (f32x4){0.f, 0.f, 0.f, 0.f};

  const int q = lane >> 4;   // k-group (frags) / row-group (C/D)
  const int r = lane & 15;   // m (A) / n (B,C/D) index within 16-tile

  for (int k0 = 0; k0 < K; k0 += BK) {
    __syncthreads();                              // LDS free (prev reads done)
    async16(aDst,           aSrc);
    async16(aDst + 16 * BK, aSrc + 16 * (size_t)K);
    async16(bDst,           bSrc);
    async16(bDst + 16 * BK, bSrc + 16 * (size_t)K);
    aSrc += BK; bSrc += BK;
    __syncthreads();                              // drains vmcnt before use

    bf16x8 af[4], bfr[4];
    #pragma unroll
    for (int mi = 0; mi < 4; ++mi)
      af[mi] = *(const bf16x8*)&As[(wm + mi * 16 + r) * BK + (q << 3)];
    #pragma unroll
    for (int ni = 0; ni < 4; ++ni)
      bfr[ni] = *(const bf16x8*)&Bs[(wn + ni * 16 + r) * BK + (q << 3)];
    #pragma unroll
    for (int mi = 0; mi < 4; ++mi)
      #pragma unroll
      for (int ni = 0; ni < 4; ++ni)
        acc[mi][ni] = __builtin_amdgcn_mfma_f32_16x16x32_bf16(
            af[mi], bfr[ni], acc[mi][ni], 0, 0, 0);
  }

  // epilogue: C/D layout col=lane&15, row=(lane>>4)*4+e  [verified m89/m91]
  #pragma unroll
  for (int ni = 0; ni < 4; ++ni) {
    const int col = n0 + wn + ni * 16 + r;
    const float bv = bias[col];
    #pragma unroll
    for (int mi = 0; mi < 4; ++mi) {
      #pragma unroll
      for (int e = 0; e < 4; ++e) {
        const int row = m0 + wm + mi * 16 + (q << 2) + e;
        float v = acc[mi][ni][e] + bv;
        if (MODE == 0 || MODE == 1) v = fmaxf(v, 0.f);
        if (MODE == 2) v *= 0.1f;
        const size_t idx = (size_t)row * ldOut + colOff + col;
        if (MODE == 0) ((unsigned short*)out)[idx] = f2b(v);
        else           ((float*)out)[idx] = v;
      }
    }
  }
}

// ---------------- LayerNorm over last dim (1024), f32 in -> bf16 out ----------------
__global__ void ln_kernel(const float* __restrict__ merged,
                          const float* __restrict__ lnw,
                          const float* __restrict__ lnb,
                          unsigned short* __restrict__ normed) {
  const int row = blockIdx.x;
  const float4 v = ((const float4*)(merged + (size_t)row * HIDDEN))[threadIdx.x];
  float s  = v.x + v.y + v.z + v.w;
  float ss = v.x * v.x + v.y * v.y + v.z * v.z + v.w * v.w;
  #pragma unroll
  for (int off = 32; off > 0; off >>= 1) {
    s  += __shfl_down(s, off, 64);
    ss += __shfl_down(ss, off, 64);
  }
  __shared__ float red[8];
  const int wvi = threadIdx.x >> 6;
  if ((threadIdx.x & 63) == 0) { red[wvi] = s; red[4 + wvi] = ss; }
  __syncthreads();
  s  = red[0] + red[1] + red[2] + red[3];
  ss = red[4] + red[5] + red[6] + red[7];
  const float mu  = s * (1.0f / HIDDEN);
  const float var = ss * (1.0f / HIDDEN) - mu * mu;
  const float rs  = rsqrtf(var + 1e-5f);
  const float4 w4 = ((const float4*)lnw)[threadIdx.x];
  const float4 b4 = ((const float4*)lnb)[threadIdx.x];
  ushort4 o;
  o.x = f2b((v.x - mu) * rs * w4.x + b4.x);
  o.y = f2b((v.y - mu) * rs * w4.y + b4.y);
  o.z = f2b((v.z - mu) * rs * w4.z + b4.z);
  o.w = f2b((v.w - mu) * rs * w4.w + b4.w);
  ((ushort4*)(normed + (size_t)row * HIDDEN))[threadIdx.x] = o;
}

extern "C" void kernel_launch(void* const* d_in, const int* in_sizes, int n_in,
                              void* d_out, int out_size, void* d_ws, size_t ws_size,
                              hipStream_t stream) {
  const int*   tokens = (const int*)d_in[0];
  const float* E      = (const float*)d_in[1];
  const float* Wc     = (const float*)d_in[2];
  const float* bc     = (const float*)d_in[3];
  const float* Wh     = (const float*)d_in[4];
  const float* bh     = (const float*)d_in[5];
  const float* Wm     = (const float*)d_in[6];
  const float* bm     = (const float*)d_in[7];
  const float* Wo     = (const float*)d_in[8];
  const float* bo     = (const float*)d_in[9];
  const float* lnw    = (const float*)d_in[10];
  const float* lnb    = (const float*)d_in[11];

  char* p = (char*)d_ws;
  unsigned short* WcT  = (unsigned short*)p; p += (size_t)HIDDEN * EMBED * 2;
  unsigned short* WhT  = (unsigned short*)p; p += (size_t)HIDDEN * EMBED * 2;
  unsigned short* WmT  = (unsigned short*)p; p += (size_t)HIDDEN * (2 * HIDDEN) * 2;
  unsigned short* WoT  = (unsigned short*)p; p += (size_t)VOCAB * HIDDEN * 2;
  unsigned short* emb  = (unsigned short*)p; p += (size_t)NROWS * EMBED * 2;
  unsigned short* hist = (unsigned short*)p; p += (size_t)NROWS * EMBED * 2;
  unsigned short* cat  = (unsigned short*)p; p += (size_t)NROWS * (2 * HIDDEN) * 2;
  float*          mrg  = (float*)p;          p += (size_t)NROWS * HIDDEN * 4;
  unsigned short* nrm  = (unsigned short*)p; p += (size_t)NROWS * HIDDEN * 2;
  float*          csum = (float*)p;          p += (size_t)BATCH * NCHUNK * EMBED * 4;
  if ((size_t)(p - (char*)d_ws) > ws_size)
    fprintf(stderr, "WS TOO SMALL: need %zu have %zu\n", (size_t)(p - (char*)d_ws), ws_size);

  // weight pre-transposes + f32->bf16 cast (GEMM consumes B^T [N,K] bf16)
  transpose_cast_kernel<<<dim3(HIDDEN / 32, EMBED / 32), 256, 0, stream>>>(Wc, WcT, EMBED, HIDDEN);
  transpose_cast_kernel<<<dim3(HIDDEN / 32, EMBED / 32), 256, 0, stream>>>(Wh, WhT, EMBED, HIDDEN);
  transpose_cast_kernel<<<dim3(HIDDEN / 32, (2 * HIDDEN) / 32), 256, 0, stream>>>(Wm, WmT, 2 * HIDDEN, HIDDEN);
  transpose_cast_kernel<<<dim3(VOCAB / 32, HIDDEN / 32), 256, 0, stream>>>(Wo, WoT, HIDDEN, VOCAB);

  gather_kernel<<<NROWS, 256, 0, stream>>>(tokens, E, emb);
  scan_sum_kernel <<<BATCH * NCHUNK, EMBED, 0, stream>>>(emb, csum);
  scan_excl_kernel<<<BATCH, EMBED, 0, stream>>>(csum);
  scan_emit_kernel<<<BATCH * NCHUNK, EMBED, 0, stream>>>(emb, csum, hist);

  // cur_enc / hist_enc -> concatenated [4096, 2048] bf16
  gemm_bt_kernel<0><<<dim3(HIDDEN / BN, NROWS / BM), 256, 0, stream>>>(
      emb, WcT, bc, cat, NROWS, HIDDEN, EMBED, 2 * HIDDEN, 0);
  gemm_bt_kernel<0><<<dim3(HIDDEN / BN, NROWS / BM), 256, 0, stream>>>(
      hist, WhT, bh, cat, NROWS, HIDDEN, EMBED, 2 * HIDDEN, HIDDEN);
  // merged = relu(cat @ Wm + bm), kept f32 for LN accuracy
  gemm_bt_kernel<1><<<dim3(HIDDEN / BN, NROWS / BM), 256, 0, stream>>>(
      cat, WmT, bm, mrg, NROWS, HIDDEN, 2 * HIDDEN, HIDDEN, 0);
  ln_kernel<<<NROWS, 256, 0, stream>>>(mrg, lnw, lnb, nrm);
  // logits = (normed @ Wo + bo) * 0.1 -> d_out f32
  gemm_bt_kernel<2><<<dim3(VOCAB / BN, NROWS / BM), 256, 0, stream>>>(
      nrm, WoT, bo, d_out, NROWS, VOCAB, HIDDEN, VOCAB, 0);
}